// Round 14
// baseline (185.989 us; speedup 1.0000x reference)
//
#include <hip/hip_runtime.h>
#include <hip/hip_bf16.h>
#include <math.h>

// Problem constants
// B=16, T=4096, E=384, H=64; M = B*T = 65536
// Y layout: [m][0..127] = K|Q (bf16, stride 128). Q is pre-scaled by
// zsc = E^-0.5*log2(e) at k_pack (folded into Wq). V goes straight to VT.

typedef __attribute__((ext_vector_type(4))) float f32x4;
typedef __attribute__((ext_vector_type(8))) __bf16 bf16x8;

#define DEVI static __device__ __forceinline__

DEVI unsigned short f2bf(float f) {
  union { float f; unsigned int u; } x; x.f = f;
  unsigned int r = x.u + 0x7fffu + ((x.u >> 16) & 1u);
  return (unsigned short)(r >> 16);
}

DEVI unsigned int cvtpk_bf16(float lo, float hi) {
  unsigned int r;
  asm("v_cvt_pk_bf16_f32 %0, %1, %2" : "=v"(r) : "v"(lo), "v"(hi));
  return r;
}

DEVI f32x4 mfma16(bf16x8 a, bf16x8 b, f32x4 c) {
  return __builtin_amdgcn_mfma_f32_16x16x32_bf16(a, b, c, 0, 0, 0);
}

// 64-elem-wide LDS rows (128 B): XOR-swizzle at 16-B granule with row&7.
DEVI bf16x8 lds_frag(const unsigned short* buf, int row, int gran) {
  return *(const bf16x8*)(buf + row * 64 + ((gran ^ (row & 7)) << 3));
}

// async 16-B global -> LDS DMA (linear dest; swizzle applied on the GLOBAL src)
DEVI void gl_lds16(const unsigned short* g, unsigned short* l) {
  __builtin_amdgcn_global_load_lds(
      (const __attribute__((address_space(1))) unsigned int*)g,
      (__attribute__((address_space(3))) unsigned int*)l, 16, 0, 0);
}

// ---------------------------------------------------------------------------
// k_pack: WT[n][k] bf16, n in [0,192) = concat(Wk,Wq,Wv) columns, k in [0,384)
// Wq columns (n in [64,128)) are pre-scaled by zsc so attention's QK^T lands
// directly in the log2-softmax domain (Q rounded once, not twice).
// ---------------------------------------------------------------------------
__global__ __launch_bounds__(256) void k_pack(const float* __restrict__ Wk,
                                              const float* __restrict__ Wq,
                                              const float* __restrict__ Wv,
                                              unsigned short* __restrict__ WT) {
  int idx = blockIdx.x * 256 + threadIdx.x;
  if (idx >= 192 * 384) return;
  int n = idx / 384, k = idx - n * 384;
  const float* W = (n < 64) ? Wk : ((n < 128) ? Wq : Wv);
  float val = W[k * 64 + (n & 63)];
  if (n >= 64 && n < 128) val *= 0.073622223f;  // 384^-0.5 * log2(e)
  WT[idx] = f2bf(val);
}

// ---------------------------------------------------------------------------
// k_proj: [K|Q|V] = x @ [Wk|Wq|Wv];  K|Q -> Y[m][128], V -> VT[b][d][t] (fused
// transpose store, packed uint2). BM=64, BN=192, BK=64; 4 waves 2x2.
// ---------------------------------------------------------------------------
__global__ __launch_bounds__(256, 4) void k_proj(const float* __restrict__ x,
                                                 const unsigned short* __restrict__ WT,
                                                 unsigned short* __restrict__ Y,
                                                 unsigned short* __restrict__ VT) {
  __shared__ __align__(16) unsigned short As[64 * 64];
  __shared__ __align__(16) unsigned short Bs[192 * 64];
  const int tid = threadIdx.x;
  const int lane = tid & 63, wid = tid >> 6;
  const int q = lane & 15, g = lane >> 4;
  const int wm = wid >> 1, wn = wid & 1;
  const int m0 = blockIdx.x * 64;

  f32x4 acc[2][6];
#pragma unroll
  for (int mt = 0; mt < 2; ++mt)
#pragma unroll
    for (int nt = 0; nt < 6; ++nt) acc[mt][nt] = f32x4{0.f, 0.f, 0.f, 0.f};

  const int ar = tid >> 2, ap = tid & 3;  // A staging: row, 16-float quarter

  for (int ks = 0; ks < 6; ++ks) {
    // stage A: x fp32 -> bf16, 64 rows x 64 k
    const float4* xp = (const float4*)(x + (size_t)(m0 + ar) * 384 + ks * 64 + ap * 16);
#pragma unroll
    for (int cc = 0; cc < 2; ++cc) {
      float4 f0 = xp[cc * 2], f1 = xp[cc * 2 + 1];
      union { unsigned short h[8]; uint4 v; } u;
      u.h[0] = f2bf(f0.x); u.h[1] = f2bf(f0.y); u.h[2] = f2bf(f0.z); u.h[3] = f2bf(f0.w);
      u.h[4] = f2bf(f1.x); u.h[5] = f2bf(f1.y); u.h[6] = f2bf(f1.z); u.h[7] = f2bf(f1.w);
      int gran = ap * 2 + cc;
      *(uint4*)(As + ar * 64 + ((gran ^ (ar & 7)) << 3)) = u.v;
    }
    // stage B: WT rows (n-major), 192 rows x 64 k
#pragma unroll
    for (int i = 0; i < 6; ++i) {
      int c = tid + 256 * i;
      int row = c >> 3, gr = c & 7;
      uint4 w = *(const uint4*)(WT + (size_t)row * 384 + ks * 64 + gr * 8);
      *(uint4*)(Bs + row * 64 + ((gr ^ (row & 7)) << 3)) = w;
    }
    __syncthreads();
#pragma unroll
    for (int kk = 0; kk < 2; ++kk) {
      bf16x8 af[2], bfv[6];
#pragma unroll
      for (int mt = 0; mt < 2; ++mt) af[mt] = lds_frag(As, wm * 32 + mt * 16 + q, kk * 4 + g);
#pragma unroll
      for (int nt = 0; nt < 6; ++nt) bfv[nt] = lds_frag(Bs, wn * 96 + nt * 16 + q, kk * 4 + g);
#pragma unroll
      for (int mt = 0; mt < 2; ++mt)
#pragma unroll
        for (int nt = 0; nt < 6; ++nt) acc[mt][nt] = mfma16(af[mt], bfv[nt], acc[mt][nt]);
    }
    __syncthreads();
  }
  // epilogue: C/D layout col=lane&15 (n), row=4*(lane>>4)+j (m).
  // n < 128 (K|Q) -> Y[m][n]; n >= 128 (V) -> VT[b][n-128][t] packed along m.
#pragma unroll
  for (int mt = 0; mt < 2; ++mt) {
    const int mrow = m0 + wm * 32 + mt * 16 + g * 4;
#pragma unroll
    for (int nt = 0; nt < 6; ++nt) {
      const int ncol = wn * 96 + nt * 16 + q;
      if (wn == 1 && nt >= 2) {
        // V: d = ncol-128 = (nt-2)*16 + q; t = mrow..mrow+3 contiguous
        const int d = (nt - 2) * 16 + q;
        const int bb = mrow >> 12, t = mrow & 4095;
        uint2 pv;
        pv.x = cvtpk_bf16(acc[mt][nt][0], acc[mt][nt][1]);
        pv.y = cvtpk_bf16(acc[mt][nt][2], acc[mt][nt][3]);
        *(uint2*)(VT + (size_t)(bb * 64 + d) * 4096 + t) = pv;
      } else {
        size_t base = (size_t)mrow * 128 + ncol;
#pragma unroll
        for (int j = 0; j < 4; ++j) Y[base + (size_t)j * 128] = f2bf(acc[mt][nt][j]);
      }
    }
  }
}

// ---------------------------------------------------------------------------
// k_attn: flash attention, causal. R13 structure (passing base, attn 58.7us):
// 512 blocks x 8 waves; QBLOCK=128, KVBLK=64; kv-parity split; 32 q-rows per
// wave (qh=0,1); 4-slot K+V ring, one barrier per 2 tiles; max-free softmax;
// kv-permuted K staging -> lane-local (register-resident) P, no P LDS buffer.
// R14 single mechanism: qh-INTERLEAVED ORDER QK0,SM0,QK1,PV0,SM1,PV1.
// With P in registers this is pure SSA dataflow (R9's failure mode -- the
// reused P LDS buffer -- no longer exists), and it hands the scheduler two
// independent MFMA clusters (QK1, PV0) to overlap with the softmax VALU
// chains (SM0, SM1). V fragments also hoist above QK to cover their ds_read
// latency. Everything else byte-identical to R13.
// ---------------------------------------------------------------------------
__global__ __launch_bounds__(512, 4) void k_attn(const unsigned short* __restrict__ Y,
                                                 const unsigned short* __restrict__ VT,
                                                 float* __restrict__ out) {
  __shared__ __align__(16) unsigned short Ks[4][64 * 64];
  __shared__ __align__(16) unsigned short Vs[4][64 * 64];

  // id -> (xcd-affine batch, size-rank): big tiles first; rank r<16 pairs with
  // r+16 so co-scheduled blocks sum to ~constant work.
  const int id = blockIdx.x;
  const int xcd = id & 7;
  const int b = xcd * 2 + ((id >> 3) & 1);
  const int rank = id >> 4;  // 0..31
  const int i = (rank < 16) ? (31 - rank) : (rank - 16);  // q-tile index
  const int q0 = i * 128;
  const int nkv = 2 * i + 2;  // KV tiles (even)

  const int tid = threadIdx.x;
  const int lane = tid & 63, wid = tid >> 6;
  const int p = wid >> 2;   // KV parity group
  const int w4 = wid & 3;   // wave within group
  const int q = lane & 15, g = lane >> 4;

  const unsigned short* Yb = Y + (size_t)b * 4096 * 128;
  const unsigned short* Vb = VT + (size_t)b * 64 * 4096;

  // stage tile at KV0 into ring slot S. K rows are staged PERMUTED so that
  // LDS row L holds global kv row kvperm(L); V rows are d-indexed (linear).
#define STAGE(S, KV0)                                                           \
  {                                                                             \
    int r = tid >> 3, grs = (tid & 7) ^ (r & 7);                                \
    int kp = (r & 32) | ((r & 12) << 1) | ((r & 16) >> 2) | (r & 3);            \
    gl_lds16(Yb + (size_t)((KV0) + kp) * 128 + grs * 8, Ks[S] + tid * 8);       \
    gl_lds16(Vb + (size_t)r * 4096 + (KV0) + grs * 8, Vs[S] + tid * 8);         \
  }

  STAGE(0, 0)
  STAGE(1, 64)
  __syncthreads();

  // Q fragments for both q-halves (already scaled by zsc via k_pack)
  bf16x8 qf[2][2];
#pragma unroll
  for (int qh = 0; qh < 2; ++qh) {
    const unsigned short* qp = Yb + (size_t)(q0 + w4 * 32 + qh * 16 + q) * 128 + 64;
    qf[qh][0] = *(const bf16x8*)(qp + g * 8);
    qf[qh][1] = *(const bf16x8*)(qp + 32 + g * 8);
  }

  f32x4 accO[2][4];
#pragma unroll
  for (int qh = 0; qh < 2; ++qh)
#pragma unroll
    for (int dt = 0; dt < 4; ++dt) accO[qh][dt] = f32x4{0.f, 0.f, 0.f, 0.f};
  float lsum[2] = {0.f, 0.f};

  // tiles this wave actually needs: waves 0,1 of a group stop one tile earlier
  const int mytiles = 2 * i + 1 + (w4 >> 1);
  const int nIt = nkv >> 1;  // = i+1

  // softmax for one q-half: mask (diag only), exp2, cvt_pk -> REGISTER bp.
  // With permuted staging, accS element (t,j) holds kv offset
  // (t>>1)*32 + g*8 + (t&1)*4 + j, which is exactly PV's B-fragment order.
#define SOFTMAX(QH, ACC, BP0, BP1)                                              \
  {                                                                             \
    if (dmw) {                                                                  \
      const int qrow = q0 + w4 * 32 + (QH) * 16 + q;                            \
      _Pragma("unroll") for (int t = 0; t < 4; ++t)                             \
        _Pragma("unroll") for (int j = 0; j < 4; ++j) {                         \
          const int kvl = ((t >> 1) << 5) + (g << 3) + ((t & 1) << 2) + j;      \
          if (kv0 + kvl > qrow) (ACC)[t][j] = -INFINITY;                        \
        }                                                                       \
    }                                                                           \
    float pp[4][4];                                                             \
    float ps0 = 0.f, ps1 = 0.f;                                                 \
    _Pragma("unroll") for (int t = 0; t < 4; ++t) {                             \
      pp[t][0] = __builtin_amdgcn_exp2f((ACC)[t][0]);                           \
      pp[t][1] = __builtin_amdgcn_exp2f((ACC)[t][1]);                           \
      pp[t][2] = __builtin_amdgcn_exp2f((ACC)[t][2]);                           \
      pp[t][3] = __builtin_amdgcn_exp2f((ACC)[t][3]);                           \
      ps0 += pp[t][0] + pp[t][1];                                               \
      ps1 += pp[t][2] + pp[t][3];                                               \
    }                                                                           \
    lsum[QH] += ps0 + ps1;                                                      \
    uint4 u0, u1;                                                               \
    u0.x = cvtpk_bf16(pp[0][0], pp[0][1]);                                      \
    u0.y = cvtpk_bf16(pp[0][2], pp[0][3]);                                      \
    u0.z = cvtpk_bf16(pp[1][0], pp[1][1]);                                      \
    u0.w = cvtpk_bf16(pp[1][2], pp[1][3]);                                      \
    u1.x = cvtpk_bf16(pp[2][0], pp[2][1]);                                      \
    u1.y = cvtpk_bf16(pp[2][2], pp[2][3]);                                      \
    u1.z = cvtpk_bf16(pp[3][0], pp[3][1]);                                      \
    u1.w = cvtpk_bf16(pp[3][2], pp[3][3]);                                      \
    (BP0) = __builtin_bit_cast(bf16x8, u0);                                     \
    (BP1) = __builtin_bit_cast(bf16x8, u1);                                     \
  }

  for (int it = 0; it < nIt; ++it) {
    const int kt = 2 * it + p;
    const int t2 = 2 * it + 2, t3 = 2 * it + 3;
    if (t2 < nkv) STAGE(t2 & 3, t2 * 64)
    if (t3 < nkv) STAGE(t3 & 3, t3 * 64)

    if (kt < mytiles) {
      const int kv0 = kt * 64;
      const unsigned short* Kc = Ks[kt & 3];
      const unsigned short* Vc = Vs[kt & 3];
      const bool dmw = (kv0 + 63 >= q0 + w4 * 32);  // diagonal tile for this wave

      // ---- K and V fragments (read once, shared by both q-halves) ----
      bf16x8 ka0[4], ka1[4];
#pragma unroll
      for (int t = 0; t < 4; ++t) {
        ka0[t] = lds_frag(Kc, t * 16 + q, g);
        ka1[t] = lds_frag(Kc, t * 16 + q, 4 + g);
      }
      bf16x8 av0[4], av1[4];
#pragma unroll
      for (int dt = 0; dt < 4; ++dt) {
        av0[dt] = lds_frag(Vc, dt * 16 + q, g);
        av1[dt] = lds_frag(Vc, dt * 16 + q, 4 + g);
      }

      // ---- QK0 ----
      f32x4 accS0[4];
      __builtin_amdgcn_s_setprio(1);
#pragma unroll
      for (int t = 0; t < 4; ++t) {
        f32x4 z = f32x4{0.f, 0.f, 0.f, 0.f};
        z = mfma16(ka0[t], qf[0][0], z);
        z = mfma16(ka1[t], qf[0][1], z);
        accS0[t] = z;
      }
      __builtin_amdgcn_s_setprio(0);

      // ---- SM0 -> bp0 (registers) ----
      bf16x8 bp00, bp01;
      SOFTMAX(0, accS0, bp00, bp01)

      // ---- QK1 (independent of SM0 -> scheduler overlaps) ----
      f32x4 accS1[4];
      __builtin_amdgcn_s_setprio(1);
#pragma unroll
      for (int t = 0; t < 4; ++t) {
        f32x4 z = f32x4{0.f, 0.f, 0.f, 0.f};
        z = mfma16(ka0[t], qf[1][0], z);
        z = mfma16(ka1[t], qf[1][1], z);
        accS1[t] = z;
      }

      // ---- PV0 (independent of SM1 below -> scheduler overlaps) ----
#pragma unroll
      for (int dt = 0; dt < 4; ++dt) {
        accO[0][dt] = mfma16(av0[dt], bp00, accO[0][dt]);
        accO[0][dt] = mfma16(av1[dt], bp01, accO[0][dt]);
      }
      __builtin_amdgcn_s_setprio(0);

      // ---- SM1 -> bp1 (registers) ----
      bf16x8 bp10, bp11;
      SOFTMAX(1, accS1, bp10, bp11)

      // ---- PV1 ----
      __builtin_amdgcn_s_setprio(1);
#pragma unroll
      for (int dt = 0; dt < 4; ++dt) {
        accO[1][dt] = mfma16(av0[dt], bp10, accO[1][dt]);
        accO[1][dt] = mfma16(av1[dt], bp11, accO[1][dt]);
      }
      __builtin_amdgcn_s_setprio(0);
    }

    __syncthreads();  // drains prefetch DMAs; frees this iteration's slots
  }
#undef STAGE
#undef SOFTMAX

  // group-local full row sums
#pragma unroll
  for (int qh = 0; qh < 2; ++qh) {
    lsum[qh] += __shfl_xor(lsum[qh], 16);
    lsum[qh] += __shfl_xor(lsum[qh], 32);
  }

  // ---- merge parity groups: O = (O_A + O_B) / (l_A + l_B) ----
  // ring is dead: accO scratch spans Ks (32 KB); l scratch at Vs base (2 KB).
  float* scrO = (float*)Ks;
  float* scrL = (float*)Vs;
  const int si = (w4 * 64 + lane) * 2;
  if (p == 1) {
#pragma unroll
    for (int qh = 0; qh < 2; ++qh) {
      float* so = scrO + (si + qh) * 16;
#pragma unroll
      for (int dt = 0; dt < 4; ++dt) *(float4*)(so + dt * 4) = *(float4*)&accO[qh][dt];
      scrL[si + qh] = lsum[qh];
    }
  }
  __syncthreads();
  if (p == 0) {
#pragma unroll
    for (int qh = 0; qh < 2; ++qh) {
      const float* so = scrO + (si + qh) * 16;
      float rl = 1.0f / (lsum[qh] + scrL[si + qh]);
      const int qrow = q0 + w4 * 32 + qh * 16 + q;
      float* op = out + (size_t)(b * 4096 + qrow) * 64;
#pragma unroll
      for (int dt = 0; dt < 4; ++dt) {
        float4 ob = *(const float4*)(so + dt * 4);
        f32x4 vO;
        vO[0] = (accO[qh][dt][0] + ob.x) * rl;
        vO[1] = (accO[qh][dt][1] + ob.y) * rl;
        vO[2] = (accO[qh][dt][2] + ob.z) * rl;
        vO[3] = (accO[qh][dt][3] + ob.w) * rl;
        *(float4*)(op + dt * 16 + g * 4) = *(float4*)&vO;
      }
    }
  }
}

// ---------------------------------------------------------------------------
extern "C" void kernel_launch(void* const* d_in, const int* in_sizes, int n_in,
                              void* d_out, int out_size, void* d_ws, size_t ws_size,
                              hipStream_t stream) {
  const float* x  = (const float*)d_in[0];
  const float* Wk = (const float*)d_in[1];
  const float* Wq = (const float*)d_in[2];
  const float* Wv = (const float*)d_in[3];
  float* out = (float*)d_out;

  // workspace layout (ushorts): WT 73728 | Y 8388608 (65536x128) | VT 4194304
  unsigned short* WT = (unsigned short*)d_ws;
  unsigned short* Y  = WT + 73728;
  unsigned short* VT = Y + 8388608;

  hipLaunchKernelGGL(k_pack, dim3(288), dim3(256), 0, stream, Wk, Wq, Wv, WT);
  hipLaunchKernelGGL(k_proj, dim3(1024), dim3(256), 0, stream, x, WT, Y, VT);
  hipLaunchKernelGGL(k_attn, dim3(512), dim3(512), 0, stream, Y, VT, out);
}

// Round 15
// 85.900 us; speedup vs baseline: 2.1652x; 2.1652x over previous
//
#include <hip/hip_runtime.h>
#include <hip/hip_bf16.h>
#include <math.h>

// Problem constants
// B=16, T=4096, E=384, H=64; M = B*T = 65536
// Y layout: [m][0..127] = K|Q (bf16, stride 128). Q is pre-scaled by
// zsc = E^-0.5*log2(e) at k_pack (folded into Wq). V goes straight to VT.

typedef __attribute__((ext_vector_type(4))) float f32x4;
typedef __attribute__((ext_vector_type(8))) __bf16 bf16x8;

#define DEVI static __device__ __forceinline__

DEVI unsigned short f2bf(float f) {
  union { float f; unsigned int u; } x; x.f = f;
  unsigned int r = x.u + 0x7fffu + ((x.u >> 16) & 1u);
  return (unsigned short)(r >> 16);
}

DEVI float bf2f(unsigned int u) {
  union { unsigned int u; float f; } x; x.u = u << 16;
  return x.f;
}

DEVI unsigned int cvtpk_bf16(float lo, float hi) {
  unsigned int r;
  asm("v_cvt_pk_bf16_f32 %0, %1, %2" : "=v"(r) : "v"(lo), "v"(hi));
  return r;
}

DEVI f32x4 mfma16(bf16x8 a, bf16x8 b, f32x4 c) {
  return __builtin_amdgcn_mfma_f32_16x16x32_bf16(a, b, c, 0, 0, 0);
}

// 64-elem-wide LDS rows (128 B): XOR-swizzle at 16-B granule with row&7.
DEVI bf16x8 lds_frag(const unsigned short* buf, int row, int gran) {
  return *(const bf16x8*)(buf + row * 64 + ((gran ^ (row & 7)) << 3));
}

// async 16-B global -> LDS DMA (linear dest; swizzle applied on the GLOBAL src)
DEVI void gl_lds16(const unsigned short* g, unsigned short* l) {
  __builtin_amdgcn_global_load_lds(
      (const __attribute__((address_space(1))) unsigned int*)g,
      (__attribute__((address_space(3))) unsigned int*)l, 16, 0, 0);
}

// ---------------------------------------------------------------------------
// k_pack: WT[n][k] bf16, n in [0,192) = concat(Wk,Wq,Wv) columns, k in [0,384)
// Wq columns (n in [64,128)) are pre-scaled by zsc.
// ---------------------------------------------------------------------------
__global__ __launch_bounds__(256) void k_pack(const float* __restrict__ Wk,
                                              const float* __restrict__ Wq,
                                              const float* __restrict__ Wv,
                                              unsigned short* __restrict__ WT) {
  int idx = blockIdx.x * 256 + threadIdx.x;
  if (idx >= 192 * 384) return;
  int n = idx / 384, k = idx - n * 384;
  const float* W = (n < 64) ? Wk : ((n < 128) ? Wq : Wv);
  float val = W[k * 64 + (n & 63)];
  if (n >= 64 && n < 128) val *= 0.073622223f;  // 384^-0.5 * log2(e)
  WT[idx] = f2bf(val);
}

// ---------------------------------------------------------------------------
// k_proj: [K|Q|V] = x @ [Wk|Wq|Wv];  K|Q -> Y[m][128], V -> VT[b][d][t] (fused
// transpose store, packed uint2). BM=64, BN=192, BK=64; 4 waves 2x2.
// ---------------------------------------------------------------------------
__global__ __launch_bounds__(256, 4) void k_proj(const float* __restrict__ x,
                                                 const unsigned short* __restrict__ WT,
                                                 unsigned short* __restrict__ Y,
                                                 unsigned short* __restrict__ VT) {
  __shared__ __align__(16) unsigned short As[64 * 64];
  __shared__ __align__(16) unsigned short Bs[192 * 64];
  const int tid = threadIdx.x;
  const int lane = tid & 63, wid = tid >> 6;
  const int q = lane & 15, g = lane >> 4;
  const int wm = wid >> 1, wn = wid & 1;
  const int m0 = blockIdx.x * 64;

  f32x4 acc[2][6];
#pragma unroll
  for (int mt = 0; mt < 2; ++mt)
#pragma unroll
    for (int nt = 0; nt < 6; ++nt) acc[mt][nt] = f32x4{0.f, 0.f, 0.f, 0.f};

  const int ar = tid >> 2, ap = tid & 3;  // A staging: row, 16-float quarter

  for (int ks = 0; ks < 6; ++ks) {
    // stage A: x fp32 -> bf16, 64 rows x 64 k
    const float4* xp = (const float4*)(x + (size_t)(m0 + ar) * 384 + ks * 64 + ap * 16);
#pragma unroll
    for (int cc = 0; cc < 2; ++cc) {
      float4 f0 = xp[cc * 2], f1 = xp[cc * 2 + 1];
      union { unsigned short h[8]; uint4 v; } u;
      u.h[0] = f2bf(f0.x); u.h[1] = f2bf(f0.y); u.h[2] = f2bf(f0.z); u.h[3] = f2bf(f0.w);
      u.h[4] = f2bf(f1.x); u.h[5] = f2bf(f1.y); u.h[6] = f2bf(f1.z); u.h[7] = f2bf(f1.w);
      int gran = ap * 2 + cc;
      *(uint4*)(As + ar * 64 + ((gran ^ (ar & 7)) << 3)) = u.v;
    }
    // stage B: WT rows (n-major), 192 rows x 64 k
#pragma unroll
    for (int i = 0; i < 6; ++i) {
      int c = tid + 256 * i;
      int row = c >> 3, gr = c & 7;
      uint4 w = *(const uint4*)(WT + (size_t)row * 384 + ks * 64 + gr * 8);
      *(uint4*)(Bs + row * 64 + ((gr ^ (row & 7)) << 3)) = w;
    }
    __syncthreads();
#pragma unroll
    for (int kk = 0; kk < 2; ++kk) {
      bf16x8 af[2], bfv[6];
#pragma unroll
      for (int mt = 0; mt < 2; ++mt) af[mt] = lds_frag(As, wm * 32 + mt * 16 + q, kk * 4 + g);
#pragma unroll
      for (int nt = 0; nt < 6; ++nt) bfv[nt] = lds_frag(Bs, wn * 96 + nt * 16 + q, kk * 4 + g);
#pragma unroll
      for (int mt = 0; mt < 2; ++mt)
#pragma unroll
        for (int nt = 0; nt < 6; ++nt) acc[mt][nt] = mfma16(af[mt], bfv[nt], acc[mt][nt]);
    }
    __syncthreads();
  }
  // epilogue: C/D layout col=lane&15 (n), row=4*(lane>>4)+j (m).
#pragma unroll
  for (int mt = 0; mt < 2; ++mt) {
    const int mrow = m0 + wm * 32 + mt * 16 + g * 4;
#pragma unroll
    for (int nt = 0; nt < 6; ++nt) {
      const int ncol = wn * 96 + nt * 16 + q;
      if (wn == 1 && nt >= 2) {
        const int d = (nt - 2) * 16 + q;
        const int bb = mrow >> 12, t = mrow & 4095;
        uint2 pv;
        pv.x = cvtpk_bf16(acc[mt][nt][0], acc[mt][nt][1]);
        pv.y = cvtpk_bf16(acc[mt][nt][2], acc[mt][nt][3]);
        *(uint2*)(VT + (size_t)(bb * 64 + d) * 4096 + t) = pv;
      } else {
        size_t base = (size_t)mrow * 128 + ncol;
#pragma unroll
        for (int j = 0; j < 4; ++j) Y[base + (size_t)j * 128] = f2bf(acc[mt][nt][j]);
      }
    }
  }
}

// ---------------------------------------------------------------------------
// k_attn: flash attention, causal. R13 internals (passing, attn 58.7us):
// 8 waves, QBLOCK=128, KVBLK=64, kv-parity split, 32 q-rows/wave (qh=0,1),
// kv-permuted K staging -> register-resident P, 4-slot ring, one barrier per
// 2 tiles, max-free softmax, in-block parity merge.
// R15 single mechanism: KV-SPLIT-K for the big tiles. q-tiles i>=16 are
// processed by TWO blocks (iteration halves [0,nH0) / [nH0,nIt)), which
// write UNNORMALIZED partials (O in bf16, l in f32) to workspace; a reduce
// kernel merges: O=(O0+O1)/(l0+l1) (linear thanks to max-free softmax).
// q-tiles i<=15 are unsplit and write out directly. 768 blocks, every job
// <=16 iterations (vs 32 before) -> the critical-CU tail halves. LPT order.
// ---------------------------------------------------------------------------
__global__ __launch_bounds__(512, 4) void k_attn(const unsigned short* __restrict__ Y,
                                                 const unsigned short* __restrict__ VT,
                                                 float* __restrict__ out,
                                                 unsigned short* __restrict__ PO,
                                                 float* __restrict__ PL) {
  __shared__ __align__(16) unsigned short Ks[4][64 * 64];
  __shared__ __align__(16) unsigned short Vs[4][64 * 64];

  // id: [2:0]=xcd, [3]=batch half, [9:4]=job idx 0..47.
  // idx<32: split jobs (i=16+(idx>>1), half=idx&1) -- launched first (LPT).
  // idx>=32: unsplit i = 47-idx (15..0, descending).
  const int id = blockIdx.x;
  const int xcd = id & 7;
  const int b = xcd * 2 + ((id >> 3) & 1);
  const int idx = id >> 4;
  int i, itBeg, itEnd, h;
  bool split;
  if (idx < 32) {
    split = true;
    i = 16 + (idx >> 1);
    h = idx & 1;
    const int nIt = i + 1, nH0 = (nIt + 1) >> 1;
    itBeg = h ? nH0 : 0;
    itEnd = h ? nIt : nH0;
  } else {
    split = false;
    i = 47 - idx;
    h = 0;
    itBeg = 0;
    itEnd = i + 1;
  }
  const int q0 = i * 128;
  const int tEnd = 2 * itEnd;  // exclusive tile bound for this block

  const int tid = threadIdx.x;
  const int lane = tid & 63, wid = tid >> 6;
  const int p = wid >> 2;   // KV parity group
  const int w4 = wid & 3;   // wave within group
  const int q = lane & 15, g = lane >> 4;

  const unsigned short* Yb = Y + (size_t)b * 4096 * 128;
  const unsigned short* Vb = VT + (size_t)b * 64 * 4096;

  // stage tile at KV0 into ring slot S. K rows are staged PERMUTED so that
  // LDS row L holds global kv row kvperm(L); V rows are d-indexed (linear).
#define STAGE(S, KV0)                                                           \
  {                                                                             \
    int r = tid >> 3, grs = (tid & 7) ^ (r & 7);                                \
    int kp = (r & 32) | ((r & 12) << 1) | ((r & 16) >> 2) | (r & 3);            \
    gl_lds16(Yb + (size_t)((KV0) + kp) * 128 + grs * 8, Ks[S] + tid * 8);       \
    gl_lds16(Vb + (size_t)r * 4096 + (KV0) + grs * 8, Vs[S] + tid * 8);         \
  }

  {
    const int tb = 2 * itBeg;
    STAGE(tb & 3, tb * 64)
    STAGE((tb + 1) & 3, (tb + 1) * 64)
  }
  __syncthreads();

  // Q fragments for both q-halves (already scaled by zsc via k_pack)
  bf16x8 qf[2][2];
#pragma unroll
  for (int qh = 0; qh < 2; ++qh) {
    const unsigned short* qp = Yb + (size_t)(q0 + w4 * 32 + qh * 16 + q) * 128 + 64;
    qf[qh][0] = *(const bf16x8*)(qp + g * 8);
    qf[qh][1] = *(const bf16x8*)(qp + 32 + g * 8);
  }

  f32x4 accO[2][4];
#pragma unroll
  for (int qh = 0; qh < 2; ++qh)
#pragma unroll
    for (int dt = 0; dt < 4; ++dt) accO[qh][dt] = f32x4{0.f, 0.f, 0.f, 0.f};
  float lsum[2] = {0.f, 0.f};

  // tiles this wave actually needs: waves 0,1 of a group stop one tile earlier
  const int mytiles = 2 * i + 1 + (w4 >> 1);

  for (int it = itBeg; it < itEnd; ++it) {
    const int kt = 2 * it + p;
    const int t2 = 2 * it + 2, t3 = 2 * it + 3;
    if (t2 < tEnd) STAGE(t2 & 3, t2 * 64)
    if (t3 < tEnd) STAGE(t3 & 3, t3 * 64)

    if (kt < mytiles) {
      const int kv0 = kt * 64;
      const unsigned short* Kc = Ks[kt & 3];
      const unsigned short* Vc = Vs[kt & 3];

      // ---- S^T = K . Q^T for both q-halves (K fragments read once).
      // Permuted staging: accS[qh][t][j] holds kv offset
      // (t>>1)*32 + g*8 + (t&1)*4 + j -- exactly PV's B-fragment order.
      bf16x8 ka0[4], ka1[4];
#pragma unroll
      for (int t = 0; t < 4; ++t) {
        ka0[t] = lds_frag(Kc, t * 16 + q, g);
        ka1[t] = lds_frag(Kc, t * 16 + q, 4 + g);
      }
      f32x4 accS[2][4];
      __builtin_amdgcn_s_setprio(1);
#pragma unroll
      for (int qh = 0; qh < 2; ++qh)
#pragma unroll
        for (int t = 0; t < 4; ++t) {
          f32x4 z = f32x4{0.f, 0.f, 0.f, 0.f};
          z = mfma16(ka0[t], qf[qh][0], z);
          z = mfma16(ka1[t], qf[qh][1], z);
          accS[qh][t] = z;
        }
      __builtin_amdgcn_s_setprio(0);

      // ---- max-free softmax per q-half; P assembled IN-REGISTER ----
      const bool dmw = (kv0 + 63 >= q0 + w4 * 32);  // diagonal tile for this wave
      bf16x8 bp[2][2];
#pragma unroll
      for (int qh = 0; qh < 2; ++qh) {
        if (dmw) {
          const int qrow = q0 + w4 * 32 + qh * 16 + q;
#pragma unroll
          for (int t = 0; t < 4; ++t)
#pragma unroll
            for (int j = 0; j < 4; ++j) {
              const int kvl = ((t >> 1) << 5) + (g << 3) + ((t & 1) << 2) + j;
              if (kv0 + kvl > qrow) accS[qh][t][j] = -INFINITY;
            }
        }
        float pp[4][4];
        float ps0 = 0.f, ps1 = 0.f;
#pragma unroll
        for (int t = 0; t < 4; ++t) {
          pp[t][0] = __builtin_amdgcn_exp2f(accS[qh][t][0]);
          pp[t][1] = __builtin_amdgcn_exp2f(accS[qh][t][1]);
          pp[t][2] = __builtin_amdgcn_exp2f(accS[qh][t][2]);
          pp[t][3] = __builtin_amdgcn_exp2f(accS[qh][t][3]);
          ps0 += pp[t][0] + pp[t][1];
          ps1 += pp[t][2] + pp[t][3];
        }
        lsum[qh] += ps0 + ps1;
        uint4 u0, u1;
        u0.x = cvtpk_bf16(pp[0][0], pp[0][1]);
        u0.y = cvtpk_bf16(pp[0][2], pp[0][3]);
        u0.z = cvtpk_bf16(pp[1][0], pp[1][1]);
        u0.w = cvtpk_bf16(pp[1][2], pp[1][3]);
        u1.x = cvtpk_bf16(pp[2][0], pp[2][1]);
        u1.y = cvtpk_bf16(pp[2][2], pp[2][3]);
        u1.z = cvtpk_bf16(pp[3][0], pp[3][1]);
        u1.w = cvtpk_bf16(pp[3][2], pp[3][3]);
        bp[qh][0] = __builtin_bit_cast(bf16x8, u0);
        bp[qh][1] = __builtin_bit_cast(bf16x8, u1);
      }

      // ---- O^T += V^T . P^T (V fragments read once, used by both q-halves)
      __builtin_amdgcn_s_setprio(1);
#pragma unroll
      for (int dt = 0; dt < 4; ++dt) {
        bf16x8 av0 = lds_frag(Vc, dt * 16 + q, g);
        bf16x8 av1 = lds_frag(Vc, dt * 16 + q, 4 + g);
#pragma unroll
        for (int qh = 0; qh < 2; ++qh) {
          accO[qh][dt] = mfma16(av0, bp[qh][0], accO[qh][dt]);
          accO[qh][dt] = mfma16(av1, bp[qh][1], accO[qh][dt]);
        }
      }
      __builtin_amdgcn_s_setprio(0);
    }

    __syncthreads();  // drains prefetch DMAs; frees this iteration's slots
  }
#undef STAGE

  // group-local full row sums
#pragma unroll
  for (int qh = 0; qh < 2; ++qh) {
    lsum[qh] += __shfl_xor(lsum[qh], 16);
    lsum[qh] += __shfl_xor(lsum[qh], 32);
  }

  // ---- in-block parity merge via LDS scratch (ring is dead) ----
  float* scrO = (float*)Ks;
  float* scrL = (float*)Vs;
  const int si = (w4 * 64 + lane) * 2;
  if (p == 1) {
#pragma unroll
    for (int qh = 0; qh < 2; ++qh) {
      float* so = scrO + (si + qh) * 16;
#pragma unroll
      for (int dt = 0; dt < 4; ++dt) *(float4*)(so + dt * 4) = *(float4*)&accO[qh][dt];
      scrL[si + qh] = lsum[qh];
    }
  }
  __syncthreads();
  if (p == 0) {
    if (!split) {
      // unsplit: normalize and write out directly (R13 path)
#pragma unroll
      for (int qh = 0; qh < 2; ++qh) {
        const float* so = scrO + (si + qh) * 16;
        float rl = 1.0f / (lsum[qh] + scrL[si + qh]);
        const int qrow = q0 + w4 * 32 + qh * 16 + q;
        float* op = out + (size_t)(b * 4096 + qrow) * 64;
#pragma unroll
        for (int dt = 0; dt < 4; ++dt) {
          float4 ob = *(const float4*)(so + dt * 4);
          f32x4 vO;
          vO[0] = (accO[qh][dt][0] + ob.x) * rl;
          vO[1] = (accO[qh][dt][1] + ob.y) * rl;
          vO[2] = (accO[qh][dt][2] + ob.z) * rl;
          vO[3] = (accO[qh][dt][3] + ob.w) * rl;
          *(float4*)(op + dt * 16 + g * 4) = *(float4*)&vO;
        }
      }
    } else {
      // split: write UNNORMALIZED partials -- O as bf16 (packed), l as f32
      const int jobj = (b << 4) + (i - 16);
      unsigned short* PO_ = PO + ((size_t)(jobj * 2 + h)) * 8192;
      float* PL_ = PL + (jobj * 2 + h) * 128;
#pragma unroll
      for (int qh = 0; qh < 2; ++qh) {
        const float* so = scrO + (si + qh) * 16;
        const float lt = lsum[qh] + scrL[si + qh];
        const int row = w4 * 32 + qh * 16 + q;
        if (g == 0) PL_[row] = lt;
#pragma unroll
        for (int dt = 0; dt < 4; ++dt) {
          float4 ob = *(const float4*)(so + dt * 4);
          uint2 pv;
          pv.x = cvtpk_bf16(accO[qh][dt][0] + ob.x, accO[qh][dt][1] + ob.y);
          pv.y = cvtpk_bf16(accO[qh][dt][2] + ob.z, accO[qh][dt][3] + ob.w);
          *(uint2*)(PO_ + row * 64 + dt * 16 + g * 4) = pv;
        }
      }
    }
  }
}

// ---------------------------------------------------------------------------
// k_red: merge split-K partials. O = (O0 + O1) / (l0 + l1).
// 256 jobs (b, i>=16) x 128 rows x 16 d-quads = 524288 threads.
// ---------------------------------------------------------------------------
__global__ __launch_bounds__(256) void k_red(const unsigned short* __restrict__ PO,
                                             const float* __restrict__ PL,
                                             float* __restrict__ out) {
  const int idx = blockIdx.x * 256 + threadIdx.x;
  const int dq = idx & 15;
  const int row = (idx >> 4) & 127;
  const int j = idx >> 11;  // 0..255 = b*16 + (i-16)
  const int b = j >> 4, i = 16 + (j & 15);

  const unsigned short* a0 = PO + ((size_t)(j * 2)) * 8192 + row * 64 + dq * 4;
  const uint2 u0 = *(const uint2*)a0;
  const uint2 u1 = *(const uint2*)(a0 + 8192);
  const float rl = 1.0f / (PL[(j * 2) * 128 + row] + PL[(j * 2 + 1) * 128 + row]);

  float4 o;
  o.x = (bf2f(u0.x & 0xffffu) + bf2f(u1.x & 0xffffu)) * rl;
  o.y = (bf2f(u0.x >> 16) + bf2f(u1.x >> 16)) * rl;
  o.z = (bf2f(u0.y & 0xffffu) + bf2f(u1.y & 0xffffu)) * rl;
  o.w = (bf2f(u0.y >> 16) + bf2f(u1.y >> 16)) * rl;
  *(float4*)(out + ((size_t)(b * 4096 + i * 128 + row)) * 64 + dq * 4) = o;
}

// ---------------------------------------------------------------------------
extern "C" void kernel_launch(void* const* d_in, const int* in_sizes, int n_in,
                              void* d_out, int out_size, void* d_ws, size_t ws_size,
                              hipStream_t stream) {
  const float* x  = (const float*)d_in[0];
  const float* Wk = (const float*)d_in[1];
  const float* Wq = (const float*)d_in[2];
  const float* Wv = (const float*)d_in[3];
  float* out = (float*)d_out;

  // workspace (ushorts): WT 73728 | Y 8388608 | VT 4194304 | PO 4194304 |
  // PL 65536 f32 (131072 ushort-equiv). Total ~34.0 MB.
  unsigned short* WT = (unsigned short*)d_ws;
  unsigned short* Y  = WT + 73728;
  unsigned short* VT = Y + 8388608;
  unsigned short* PO = VT + 4194304;
  float*          PL = (float*)(PO + 4194304);

  hipLaunchKernelGGL(k_pack, dim3(288), dim3(256), 0, stream, Wk, Wq, Wv, WT);
  hipLaunchKernelGGL(k_proj, dim3(1024), dim3(256), 0, stream, x, WT, Y, VT);
  hipLaunchKernelGGL(k_attn, dim3(768), dim3(512), 0, stream, Y, VT, out, PO, PL);
  hipLaunchKernelGGL(k_red, dim3(2048), dim3(256), 0, stream, PO, PL, out);
}

// Round 16
// 84.558 us; speedup vs baseline: 2.1995x; 1.0159x over previous
//
#include <hip/hip_runtime.h>
#include <hip/hip_bf16.h>
#include <math.h>

// Problem constants
// B=16, T=4096, E=384, H=64; M = B*T = 65536
// Y layout: [m][0..127] = K|Q (bf16, stride 128). Q is pre-scaled by
// zsc = E^-0.5*log2(e) at k_pack (folded into Wq). V goes straight to VT.

typedef __attribute__((ext_vector_type(4))) float f32x4;
typedef __attribute__((ext_vector_type(8))) __bf16 bf16x8;

#define DEVI static __device__ __forceinline__

DEVI unsigned short f2bf(float f) {
  union { float f; unsigned int u; } x; x.f = f;
  unsigned int r = x.u + 0x7fffu + ((x.u >> 16) & 1u);
  return (unsigned short)(r >> 16);
}

DEVI float bf2f(unsigned int u) {
  union { unsigned int u; float f; } x; x.u = u << 16;
  return x.f;
}

DEVI unsigned int cvtpk_bf16(float lo, float hi) {
  unsigned int r;
  asm("v_cvt_pk_bf16_f32 %0, %1, %2" : "=v"(r) : "v"(lo), "v"(hi));
  return r;
}

DEVI f32x4 mfma16(bf16x8 a, bf16x8 b, f32x4 c) {
  return __builtin_amdgcn_mfma_f32_16x16x32_bf16(a, b, c, 0, 0, 0);
}

// 64-elem-wide LDS rows (128 B): XOR-swizzle at 16-B granule with row&7.
DEVI bf16x8 lds_frag(const unsigned short* buf, int row, int gran) {
  return *(const bf16x8*)(buf + row * 64 + ((gran ^ (row & 7)) << 3));
}

// async 16-B global -> LDS DMA (linear dest; swizzle applied on the GLOBAL src)
DEVI void gl_lds16(const unsigned short* g, unsigned short* l) {
  __builtin_amdgcn_global_load_lds(
      (const __attribute__((address_space(1))) unsigned int*)g,
      (__attribute__((address_space(3))) unsigned int*)l, 16, 0, 0);
}

// ---------------------------------------------------------------------------
// k_pack: WT[n][k] bf16, n in [0,192) = concat(Wk,Wq,Wv) columns, k in [0,384)
// Wq columns (n in [64,128)) are pre-scaled by zsc.
// ---------------------------------------------------------------------------
__global__ __launch_bounds__(256) void k_pack(const float* __restrict__ Wk,
                                              const float* __restrict__ Wq,
                                              const float* __restrict__ Wv,
                                              unsigned short* __restrict__ WT) {
  int idx = blockIdx.x * 256 + threadIdx.x;
  if (idx >= 192 * 384) return;
  int n = idx / 384, k = idx - n * 384;
  const float* W = (n < 64) ? Wk : ((n < 128) ? Wq : Wv);
  float val = W[k * 64 + (n & 63)];
  if (n >= 64 && n < 128) val *= 0.073622223f;  // 384^-0.5 * log2(e)
  WT[idx] = f2bf(val);
}

// ---------------------------------------------------------------------------
// k_proj: [K|Q|V] = x @ [Wk|Wq|Wv];  K|Q -> Y[m][128], V -> VT[b][d][t] (fused
// transpose store, packed uint2). BM=64, BN=192, BK=64; 4 waves 2x2.
// ---------------------------------------------------------------------------
__global__ __launch_bounds__(256, 4) void k_proj(const float* __restrict__ x,
                                                 const unsigned short* __restrict__ WT,
                                                 unsigned short* __restrict__ Y,
                                                 unsigned short* __restrict__ VT) {
  __shared__ __align__(16) unsigned short As[64 * 64];
  __shared__ __align__(16) unsigned short Bs[192 * 64];
  const int tid = threadIdx.x;
  const int lane = tid & 63, wid = tid >> 6;
  const int q = lane & 15, g = lane >> 4;
  const int wm = wid >> 1, wn = wid & 1;
  const int m0 = blockIdx.x * 64;

  f32x4 acc[2][6];
#pragma unroll
  for (int mt = 0; mt < 2; ++mt)
#pragma unroll
    for (int nt = 0; nt < 6; ++nt) acc[mt][nt] = f32x4{0.f, 0.f, 0.f, 0.f};

  const int ar = tid >> 2, ap = tid & 3;  // A staging: row, 16-float quarter

  for (int ks = 0; ks < 6; ++ks) {
    // stage A: x fp32 -> bf16, 64 rows x 64 k
    const float4* xp = (const float4*)(x + (size_t)(m0 + ar) * 384 + ks * 64 + ap * 16);
#pragma unroll
    for (int cc = 0; cc < 2; ++cc) {
      float4 f0 = xp[cc * 2], f1 = xp[cc * 2 + 1];
      union { unsigned short h[8]; uint4 v; } u;
      u.h[0] = f2bf(f0.x); u.h[1] = f2bf(f0.y); u.h[2] = f2bf(f0.z); u.h[3] = f2bf(f0.w);
      u.h[4] = f2bf(f1.x); u.h[5] = f2bf(f1.y); u.h[6] = f2bf(f1.z); u.h[7] = f2bf(f1.w);
      int gran = ap * 2 + cc;
      *(uint4*)(As + ar * 64 + ((gran ^ (ar & 7)) << 3)) = u.v;
    }
    // stage B: WT rows (n-major), 192 rows x 64 k
#pragma unroll
    for (int i = 0; i < 6; ++i) {
      int c = tid + 256 * i;
      int row = c >> 3, gr = c & 7;
      uint4 w = *(const uint4*)(WT + (size_t)row * 384 + ks * 64 + gr * 8);
      *(uint4*)(Bs + row * 64 + ((gr ^ (row & 7)) << 3)) = w;
    }
    __syncthreads();
#pragma unroll
    for (int kk = 0; kk < 2; ++kk) {
      bf16x8 af[2], bfv[6];
#pragma unroll
      for (int mt = 0; mt < 2; ++mt) af[mt] = lds_frag(As, wm * 32 + mt * 16 + q, kk * 4 + g);
#pragma unroll
      for (int nt = 0; nt < 6; ++nt) bfv[nt] = lds_frag(Bs, wn * 96 + nt * 16 + q, kk * 4 + g);
#pragma unroll
      for (int mt = 0; mt < 2; ++mt)
#pragma unroll
        for (int nt = 0; nt < 6; ++nt) acc[mt][nt] = mfma16(af[mt], bfv[nt], acc[mt][nt]);
    }
    __syncthreads();
  }
  // epilogue: C/D layout col=lane&15 (n), row=4*(lane>>4)+j (m).
#pragma unroll
  for (int mt = 0; mt < 2; ++mt) {
    const int mrow = m0 + wm * 32 + mt * 16 + g * 4;
#pragma unroll
    for (int nt = 0; nt < 6; ++nt) {
      const int ncol = wn * 96 + nt * 16 + q;
      if (wn == 1 && nt >= 2) {
        const int d = (nt - 2) * 16 + q;
        const int bb = mrow >> 12, t = mrow & 4095;
        uint2 pv;
        pv.x = cvtpk_bf16(acc[mt][nt][0], acc[mt][nt][1]);
        pv.y = cvtpk_bf16(acc[mt][nt][2], acc[mt][nt][3]);
        *(uint2*)(VT + (size_t)(bb * 64 + d) * 4096 + t) = pv;
      } else {
        size_t base = (size_t)mrow * 128 + ncol;
#pragma unroll
        for (int j = 0; j < 4; ++j) Y[base + (size_t)j * 128] = f2bf(acc[mt][nt][j]);
      }
    }
  }
}

// ---------------------------------------------------------------------------
// k_attn: flash attention, causal. R13/R15 internals (passing): 8 waves,
// QBLOCK=128, KVBLK=64, kv-parity split, 32 q-rows/wave (qh=0,1), kv-permuted
// K staging -> register-resident P, 4-slot ring, one barrier per 2 tiles,
// max-free softmax, in-block parity merge.
// R16 single mechanism: UNIFORM 2-WAY SPLIT + strict LPT order. Every q-tile
// (i=0..31) is two jobs (kv halves); idx 0..63 maps i = 31-(idx>>1) so the
// dispatch order is length-descending (16,16,16,15,...). All jobs write
// unnormalized partials (O bf16, l f32); k_red merges everything. Removes
// R15's second-wave long-job tail (makespan ~24 -> ~17 iter-equivalents)
// and deletes the unsplit epilogue branch.
// ---------------------------------------------------------------------------
__global__ __launch_bounds__(512, 4) void k_attn(const unsigned short* __restrict__ Y,
                                                 const unsigned short* __restrict__ VT,
                                                 unsigned short* __restrict__ PO,
                                                 float* __restrict__ PL) {
  __shared__ __align__(16) unsigned short Ks[4][64 * 64];
  __shared__ __align__(16) unsigned short Vs[4][64 * 64];

  // id: [2:0]=xcd, [3]=batch half, [9:4]=job idx 0..63 (length-descending).
  const int id = blockIdx.x;
  const int xcd = id & 7;
  const int b = xcd * 2 + ((id >> 3) & 1);
  const int idx = id >> 4;
  const int i = 31 - (idx >> 1);  // q-tile index, big first (LPT)
  const int h = idx & 1;          // kv half
  const int nIt = i + 1, nH0 = (nIt + 1) >> 1;
  const int itBeg = h ? nH0 : 0;
  const int itEnd = h ? nIt : nH0;
  const int q0 = i * 128;
  const int tEnd = 2 * itEnd;  // exclusive tile bound for this block

  const int tid = threadIdx.x;
  const int lane = tid & 63, wid = tid >> 6;
  const int p = wid >> 2;   // KV parity group
  const int w4 = wid & 3;   // wave within group
  const int q = lane & 15, g = lane >> 4;

  const unsigned short* Yb = Y + (size_t)b * 4096 * 128;
  const unsigned short* Vb = VT + (size_t)b * 64 * 4096;

  // stage tile at KV0 into ring slot S. K rows are staged PERMUTED so that
  // LDS row L holds global kv row kvperm(L); V rows are d-indexed (linear).
#define STAGE(S, KV0)                                                           \
  {                                                                             \
    int r = tid >> 3, grs = (tid & 7) ^ (r & 7);                                \
    int kp = (r & 32) | ((r & 12) << 1) | ((r & 16) >> 2) | (r & 3);            \
    gl_lds16(Yb + (size_t)((KV0) + kp) * 128 + grs * 8, Ks[S] + tid * 8);       \
    gl_lds16(Vb + (size_t)r * 4096 + (KV0) + grs * 8, Vs[S] + tid * 8);         \
  }

  {
    const int tb = 2 * itBeg;
    STAGE(tb & 3, tb * 64)
    STAGE((tb + 1) & 3, (tb + 1) * 64)
  }
  __syncthreads();

  // Q fragments for both q-halves (already scaled by zsc via k_pack)
  bf16x8 qf[2][2];
#pragma unroll
  for (int qh = 0; qh < 2; ++qh) {
    const unsigned short* qp = Yb + (size_t)(q0 + w4 * 32 + qh * 16 + q) * 128 + 64;
    qf[qh][0] = *(const bf16x8*)(qp + g * 8);
    qf[qh][1] = *(const bf16x8*)(qp + 32 + g * 8);
  }

  f32x4 accO[2][4];
#pragma unroll
  for (int qh = 0; qh < 2; ++qh)
#pragma unroll
    for (int dt = 0; dt < 4; ++dt) accO[qh][dt] = f32x4{0.f, 0.f, 0.f, 0.f};
  float lsum[2] = {0.f, 0.f};

  // tiles this wave actually needs: waves 0,1 of a group stop one tile earlier
  const int mytiles = 2 * i + 1 + (w4 >> 1);

  for (int it = itBeg; it < itEnd; ++it) {
    const int kt = 2 * it + p;
    const int t2 = 2 * it + 2, t3 = 2 * it + 3;
    if (t2 < tEnd) STAGE(t2 & 3, t2 * 64)
    if (t3 < tEnd) STAGE(t3 & 3, t3 * 64)

    if (kt < mytiles) {
      const int kv0 = kt * 64;
      const unsigned short* Kc = Ks[kt & 3];
      const unsigned short* Vc = Vs[kt & 3];

      // ---- S^T = K . Q^T for both q-halves (K fragments read once).
      // Permuted staging: accS[qh][t][j] holds kv offset
      // (t>>1)*32 + g*8 + (t&1)*4 + j -- exactly PV's B-fragment order.
      bf16x8 ka0[4], ka1[4];
#pragma unroll
      for (int t = 0; t < 4; ++t) {
        ka0[t] = lds_frag(Kc, t * 16 + q, g);
        ka1[t] = lds_frag(Kc, t * 16 + q, 4 + g);
      }
      f32x4 accS[2][4];
      __builtin_amdgcn_s_setprio(1);
#pragma unroll
      for (int qh = 0; qh < 2; ++qh)
#pragma unroll
        for (int t = 0; t < 4; ++t) {
          f32x4 z = f32x4{0.f, 0.f, 0.f, 0.f};
          z = mfma16(ka0[t], qf[qh][0], z);
          z = mfma16(ka1[t], qf[qh][1], z);
          accS[qh][t] = z;
        }
      __builtin_amdgcn_s_setprio(0);

      // ---- max-free softmax per q-half; P assembled IN-REGISTER ----
      const bool dmw = (kv0 + 63 >= q0 + w4 * 32);  // diagonal tile for this wave
      bf16x8 bp[2][2];
#pragma unroll
      for (int qh = 0; qh < 2; ++qh) {
        if (dmw) {
          const int qrow = q0 + w4 * 32 + qh * 16 + q;
#pragma unroll
          for (int t = 0; t < 4; ++t)
#pragma unroll
            for (int j = 0; j < 4; ++j) {
              const int kvl = ((t >> 1) << 5) + (g << 3) + ((t & 1) << 2) + j;
              if (kv0 + kvl > qrow) accS[qh][t][j] = -INFINITY;
            }
        }
        float pp[4][4];
        float ps0 = 0.f, ps1 = 0.f;
#pragma unroll
        for (int t = 0; t < 4; ++t) {
          pp[t][0] = __builtin_amdgcn_exp2f(accS[qh][t][0]);
          pp[t][1] = __builtin_amdgcn_exp2f(accS[qh][t][1]);
          pp[t][2] = __builtin_amdgcn_exp2f(accS[qh][t][2]);
          pp[t][3] = __builtin_amdgcn_exp2f(accS[qh][t][3]);
          ps0 += pp[t][0] + pp[t][1];
          ps1 += pp[t][2] + pp[t][3];
        }
        lsum[qh] += ps0 + ps1;
        uint4 u0, u1;
        u0.x = cvtpk_bf16(pp[0][0], pp[0][1]);
        u0.y = cvtpk_bf16(pp[0][2], pp[0][3]);
        u0.z = cvtpk_bf16(pp[1][0], pp[1][1]);
        u0.w = cvtpk_bf16(pp[1][2], pp[1][3]);
        u1.x = cvtpk_bf16(pp[2][0], pp[2][1]);
        u1.y = cvtpk_bf16(pp[2][2], pp[2][3]);
        u1.z = cvtpk_bf16(pp[3][0], pp[3][1]);
        u1.w = cvtpk_bf16(pp[3][2], pp[3][3]);
        bp[qh][0] = __builtin_bit_cast(bf16x8, u0);
        bp[qh][1] = __builtin_bit_cast(bf16x8, u1);
      }

      // ---- O^T += V^T . P^T (V fragments read once, used by both q-halves)
      __builtin_amdgcn_s_setprio(1);
#pragma unroll
      for (int dt = 0; dt < 4; ++dt) {
        bf16x8 av0 = lds_frag(Vc, dt * 16 + q, g);
        bf16x8 av1 = lds_frag(Vc, dt * 16 + q, 4 + g);
#pragma unroll
        for (int qh = 0; qh < 2; ++qh) {
          accO[qh][dt] = mfma16(av0, bp[qh][0], accO[qh][dt]);
          accO[qh][dt] = mfma16(av1, bp[qh][1], accO[qh][dt]);
        }
      }
      __builtin_amdgcn_s_setprio(0);
    }

    __syncthreads();  // drains prefetch DMAs; frees this iteration's slots
  }
#undef STAGE

  // group-local full row sums
#pragma unroll
  for (int qh = 0; qh < 2; ++qh) {
    lsum[qh] += __shfl_xor(lsum[qh], 16);
    lsum[qh] += __shfl_xor(lsum[qh], 32);
  }

  // ---- in-block parity merge via LDS scratch (ring is dead) ----
  float* scrO = (float*)Ks;
  float* scrL = (float*)Vs;
  const int si = (w4 * 64 + lane) * 2;
  if (p == 1) {
#pragma unroll
    for (int qh = 0; qh < 2; ++qh) {
      float* so = scrO + (si + qh) * 16;
#pragma unroll
      for (int dt = 0; dt < 4; ++dt) *(float4*)(so + dt * 4) = *(float4*)&accO[qh][dt];
      scrL[si + qh] = lsum[qh];
    }
  }
  __syncthreads();
  if (p == 0) {
    // write UNNORMALIZED partials -- O as bf16 (packed), l as f32
    const int jobj = (b << 5) + i;  // 0..511
    unsigned short* PO_ = PO + ((size_t)(jobj * 2 + h)) * 8192;
    float* PL_ = PL + (jobj * 2 + h) * 128;
#pragma unroll
    for (int qh = 0; qh < 2; ++qh) {
      const float* so = scrO + (si + qh) * 16;
      const float lt = lsum[qh] + scrL[si + qh];
      const int row = w4 * 32 + qh * 16 + q;
      if (g == 0) PL_[row] = lt;
#pragma unroll
      for (int dt = 0; dt < 4; ++dt) {
        float4 ob = *(const float4*)(so + dt * 4);
        uint2 pv;
        pv.x = cvtpk_bf16(accO[qh][dt][0] + ob.x, accO[qh][dt][1] + ob.y);
        pv.y = cvtpk_bf16(accO[qh][dt][2] + ob.z, accO[qh][dt][3] + ob.w);
        *(uint2*)(PO_ + row * 64 + dt * 16 + g * 4) = pv;
      }
    }
  }
}

// ---------------------------------------------------------------------------
// k_red: merge split-K partials. O = (O0 + O1) / (l0 + l1).
// 512 jobs (b, i) x 128 rows x 16 d-quads = 1048576 threads.
// ---------------------------------------------------------------------------
__global__ __launch_bounds__(256) void k_red(const unsigned short* __restrict__ PO,
                                             const float* __restrict__ PL,
                                             float* __restrict__ out) {
  const int idx = blockIdx.x * 256 + threadIdx.x;
  const int dq = idx & 15;
  const int row = (idx >> 4) & 127;
  const int j = idx >> 11;  // 0..511 = b*32 + i
  const int b = j >> 5, i = j & 31;

  const unsigned short* a0 = PO + ((size_t)(j * 2)) * 8192 + row * 64 + dq * 4;
  const uint2 u0 = *(const uint2*)a0;
  const uint2 u1 = *(const uint2*)(a0 + 8192);
  const float rl = 1.0f / (PL[(j * 2) * 128 + row] + PL[(j * 2 + 1) * 128 + row]);

  float4 o;
  o.x = (bf2f(u0.x & 0xffffu) + bf2f(u1.x & 0xffffu)) * rl;
  o.y = (bf2f(u0.x >> 16) + bf2f(u1.x >> 16)) * rl;
  o.z = (bf2f(u0.y & 0xffffu) + bf2f(u1.y & 0xffffu)) * rl;
  o.w = (bf2f(u0.y >> 16) + bf2f(u1.y >> 16)) * rl;
  *(float4*)(out + ((size_t)(b * 4096 + i * 128 + row)) * 64 + dq * 4) = o;
}

// ---------------------------------------------------------------------------
extern "C" void kernel_launch(void* const* d_in, const int* in_sizes, int n_in,
                              void* d_out, int out_size, void* d_ws, size_t ws_size,
                              hipStream_t stream) {
  const float* x  = (const float*)d_in[0];
  const float* Wk = (const float*)d_in[1];
  const float* Wq = (const float*)d_in[2];
  const float* Wv = (const float*)d_in[3];
  float* out = (float*)d_out;

  // workspace (ushorts): WT 73728 | Y 8388608 | VT 4194304 | PO 8388608 |
  // PL 131072 f32 (262144 ushort-equiv). Total ~42.6 MB.
  unsigned short* WT = (unsigned short*)d_ws;
  unsigned short* Y  = WT + 73728;
  unsigned short* VT = Y + 8388608;
  unsigned short* PO = VT + 4194304;
  float*          PL = (float*)(PO + 8388608);

  hipLaunchKernelGGL(k_pack, dim3(288), dim3(256), 0, stream, Wk, Wq, Wv, WT);
  hipLaunchKernelGGL(k_proj, dim3(1024), dim3(256), 0, stream, x, WT, Y, VT);
  hipLaunchKernelGGL(k_attn, dim3(1024), dim3(512), 0, stream, Y, VT, PO, PL);
  hipLaunchKernelGGL(k_red, dim3(4096), dim3(256), 0, stream, PO, PL, out);
}